// Round 20
// baseline (422.035 us; speedup 1.0000x reference)
//
#include <hip/hip_runtime.h>
#include <hip/hip_bf16.h>

#define N_NODES 100000
#define N_EDGES 600000
#define DIM     128
#define N_REL   8
#define N_GRAPH 64
#define N_LAYER 3
#define NR      (N_NODES * N_REL)   // 800000
#define NB1     782                 // ceil(NR / 1024)

typedef __attribute__((ext_vector_type(4))) float float4v;
typedef __attribute__((ext_vector_type(2))) float float2v;
typedef unsigned long long ull;

// XOR-swizzle, 8-B granules, 128-B rows (B fp8 tiles): 16 granules/row
__device__ __forceinline__ int gswz8(int row, int g) {
    return row * 16 + (g ^ (row & 15));
}

// ---------------- fused prep: edge hist + x0 gather + weight prep + gcnt ----------------
#define W8_TOTAL (N_LAYER * 9 * 8192)   // 221184
#define PB_HIST  2344                   // ceil(600000/256)
#define PB_GATH  12500                  // 100000*32/256
#define PB_WPRE  864                    // 221184/256
#define PB_BCNT  1                      // binary-search block (NO atomics — r17's 100k
                                        // contended atomicAdds onto 64 ints cost 540 us)
#define PB_TOTAL (PB_HIST + PB_GATH + PB_WPRE + PB_BCNT)

__global__ __launch_bounds__(256) void k_prep(
    const int* __restrict__ ei, const int* __restrict__ et, int* __restrict__ counts,
    const int* __restrict__ nt, const float* __restrict__ emb, unsigned int* __restrict__ x8,
    const float* __restrict__ relw, const float* __restrict__ rootw,
    unsigned short* __restrict__ W8,
    const int* __restrict__ batch, int* __restrict__ gcnt)
{
    const int b = blockIdx.x, t = threadIdx.x;
    if (b < PB_HIST) {
        int e = b * 256 + t;
        if (e < N_EDGES) {
            int seg = ei[N_EDGES + e] * N_REL + et[e];
            atomicAdd(&counts[seg], 1);
        }
    } else if (b < PB_HIST + PB_GATH) {
        int gid = (b - PB_HIST) * 256 + t;        // < N_NODES*32 exactly
        int n = gid >> 5, up = gid & 31;
        const float* row = emb + (size_t)nt[n] * DIM;
        int p0 = up * 4;
        float f0 = row[((p0 + 0) & 7) * 16 + ((p0 + 0) >> 3)];
        float f1 = row[((p0 + 1) & 7) * 16 + ((p0 + 1) >> 3)];
        float f2 = row[((p0 + 2) & 7) * 16 + ((p0 + 2) >> 3)];
        float f3 = row[((p0 + 3) & 7) * 16 + ((p0 + 3) >> 3)];
        int u = __builtin_amdgcn_cvt_pk_fp8_f32(f0, f1, 0, false);
        u = __builtin_amdgcn_cvt_pk_fp8_f32(f2, f3, u, true);
        x8[gid] = (unsigned int)u;
    } else if (b < PB_HIST + PB_GATH + PB_WPRE) {
        int gid = (b - PB_HIST - PB_GATH) * 256 + t;   // < W8_TOTAL exactly
        int l = gid / (9 * 8192);
        int rem = gid - l * 9 * 8192;
        int r = rem >> 13;                 // plane 0..8
        int idx = rem & 8191;
        int n = idx >> 6, p2 = idx & 63;
        int pos0 = 2 * p2, pos1 = 2 * p2 + 1;
        int k0 = (pos0 & 7) * 16 + (pos0 >> 3);
        int k1 = (pos1 & 7) * 16 + (pos1 >> 3);
        float w0, w1;
        if (r < 8) {
            const float* base = relw + ((size_t)(l * 8 + r) * 128) * 128 + n;
            w0 = base[(size_t)k0 * 128];
            w1 = base[(size_t)k1 * 128];
        } else {
            const float* base = rootw + (size_t)l * 128 * 128 + n;
            w0 = base[(size_t)k0 * 128];
            w1 = base[(size_t)k1 * 128];
        }
        int pk = __builtin_amdgcn_cvt_pk_fp8_f32(w0, w1, 0, false);
        W8[gid] = (unsigned short)(pk & 0xffff);
    } else {
        // gcnt via binary search over sorted batch (plain stores, no atomics)
        int g = t;
        if (g < N_GRAPH) {
            int lo = 0, hi = N_NODES;
            while (lo < hi) { int mid = (lo + hi) >> 1; if (batch[mid] < g) lo = mid + 1; else hi = mid; }
            int start = lo;
            lo = 0; hi = N_NODES;
            while (lo < hi) { int mid = (lo + hi) >> 1; if (batch[mid] < g + 1) lo = mid + 1; else hi = mid; }
            gcnt[g] = lo - start;
        }
    }
}

__global__ __launch_bounds__(256) void k_scan1(const int* __restrict__ cnts,
                                               int* __restrict__ part,
                                               int* __restrict__ bsum) {
    __shared__ int sh[256];
    int t = threadIdx.x;
    int base = blockIdx.x * 1024 + t * 4;
    int v0 = (base + 0 < NR) ? cnts[base + 0] : 0;
    int v1 = (base + 1 < NR) ? cnts[base + 1] : 0;
    int v2 = (base + 2 < NR) ? cnts[base + 2] : 0;
    int v3 = (base + 3 < NR) ? cnts[base + 3] : 0;
    int tot = v0 + v1 + v2 + v3;
    sh[t] = tot;
    __syncthreads();
    for (int off = 1; off < 256; off <<= 1) {
        int x = (t >= off) ? sh[t - off] : 0;
        __syncthreads();
        sh[t] += x;
        __syncthreads();
    }
    int exc = sh[t] - tot;
    if (base + 0 < NR) part[base + 0] = exc;
    if (base + 1 < NR) part[base + 1] = exc + v0;
    if (base + 2 < NR) part[base + 2] = exc + v0 + v1;
    if (base + 3 < NR) part[base + 3] = exc + v0 + v1 + v2;
    if (t == 255) bsum[blockIdx.x] = sh[t];
}

__global__ __launch_bounds__(1024) void k_scan2(int* __restrict__ bsum, int nb) {
    __shared__ int sh[1024];
    int t = threadIdx.x;
    int v = (t < nb) ? bsum[t] : 0;
    sh[t] = v;
    __syncthreads();
    for (int off = 1; off < 1024; off <<= 1) {
        int x = (t >= off) ? sh[t - off] : 0;
        __syncthreads();
        sh[t] += x;
        __syncthreads();
    }
    if (t < nb) bsum[t] = sh[t] - v;   // exclusive block offsets
}

__global__ void k_scan3(const int* __restrict__ part, const int* __restrict__ bsum,
                        int* __restrict__ rowptr, int* __restrict__ cursor) {
    int i = blockIdx.x * 256 + threadIdx.x;
    if (i < NR) {
        int v = part[i] + bsum[i >> 10];
        rowptr[i] = v;
        cursor[i] = v;
    }
    if (i == 0) rowptr[NR] = N_EDGES;
}

__global__ void k_scatter(const int* __restrict__ ei, const int* __restrict__ et,
                          int* __restrict__ cursor, int* __restrict__ srcs) {
    int e = blockIdx.x * 256 + threadIdx.x;
    if (e < N_EDGES) {
        int seg = ei[N_EDGES + e] * N_REL + et[e];
        int p = atomicAdd(&cursor[seg], 1);
        srcs[p] = ei[e];
    }
}

// ---------------- per-dst aggregation: 4 nodes/wave, fp8 in, FRAGMENT-ORDER fp8 out ----
// Quarter q (16 lanes) owns node 4w+q; lane j covers byte positions 8j..8j+7.
// Wave-uniform maxc loop: every __shfl executes with all 64 lanes active (bpermute
// returns 0 from EXEC-inactive source lanes — divergent-loop shfl is UB; see r14).
// Unroll-4: 4 independent gathers in flight per quarter (r19 was latency-bound at 2).
__global__ __launch_bounds__(256) void k_agg(
    const unsigned int* __restrict__ x8,    // [N][32] fp8 rows (pi order)
    const int* __restrict__ rowptr,         // [NR+1], seg = dst*8 + rel
    const int* __restrict__ srcs,           // [E] sorted by seg
    unsigned int* __restrict__ Ag8,         // [8] fragment-order planes
    int d0, int rows, int srows)
{
    const int t = threadIdx.x;
    const int wv = t >> 6, lane = t & 63;
    const int q = lane >> 4, j = lane & 15;
    const int nb0 = (blockIdx.x * 4 + wv) * 4;     // first local node of this wave
    if (nb0 >= rows) return;
    const int myn = nb0 + q;
    const bool nvalid = (myn < rows);

    int pr = 0;
    {
        int idx = (d0 + nb0) * 8 + lane;
        if (idx > NR) idx = NR;
        if (lane < 33) pr = rowptr[idx];
    }
    const int P0 = __shfl(pr, 0);
    const int Dtot = __shfl(pr, 32) - P0;

    int my_src = 0;
    if (lane < Dtot) my_src = srcs[P0 + lane];

    const uint2* x2p = (const uint2*)x8;           // row = 16 uint2
    uint2* Agf = (uint2*)Ag8;

    for (int r = 0; r < 8; ++r) {
        int e0 = __shfl(pr, q * 8 + r);
        int e1 = __shfl(pr, q * 8 + r + 1);
        int cnt = e1 - e0;                         // quarter-uniform
        int m1 = max(cnt, __shfl_xor(cnt, 16));
        int maxc = max(m1, __shfl_xor(m1, 32));    // wave max
        float2v A0 = {0.f, 0.f}, A1 = {0.f, 0.f}, A2 = {0.f, 0.f}, A3 = {0.f, 0.f};
        int k = 0;
        for (; k + 4 <= maxc; k += 4) {            // wave-uniform, 4 loads in flight
            int s0, s1, s2, s3;
            {
                int r0 = e0 + k - P0,     r1 = e0 + k + 1 - P0;
                int r2 = e0 + k + 2 - P0, r3 = e0 + k + 3 - P0;
                s0 = __shfl(my_src, r0 & 63);
                s1 = __shfl(my_src, r1 & 63);
                s2 = __shfl(my_src, r2 & 63);
                s3 = __shfl(my_src, r3 & 63);
                if (r0 >= 64) s0 = srcs[e0 + k];
                if (r1 >= 64) s1 = srcs[e0 + k + 1];
                if (r2 >= 64) s2 = srcs[e0 + k + 2];
                if (r3 >= 64) s3 = srcs[e0 + k + 3];
            }
            bool v0 = (k < cnt), v1 = (k + 1 < cnt);
            bool v2 = (k + 2 < cnt), v3 = (k + 3 < cnt);
            uint2 u0, u1, u2, u3;
            if (v0) u0 = x2p[(size_t)s0 * 16 + j];
            if (v1) u1 = x2p[(size_t)s1 * 16 + j];
            if (v2) u2 = x2p[(size_t)s2 * 16 + j];
            if (v3) u3 = x2p[(size_t)s3 * 16 + j];
            if (v0) {
                A0 += __builtin_amdgcn_cvt_pk_f32_fp8((int)u0.x, false);
                A1 += __builtin_amdgcn_cvt_pk_f32_fp8((int)u0.x, true);
                A2 += __builtin_amdgcn_cvt_pk_f32_fp8((int)u0.y, false);
                A3 += __builtin_amdgcn_cvt_pk_f32_fp8((int)u0.y, true);
            }
            if (v1) {
                A0 += __builtin_amdgcn_cvt_pk_f32_fp8((int)u1.x, false);
                A1 += __builtin_amdgcn_cvt_pk_f32_fp8((int)u1.x, true);
                A2 += __builtin_amdgcn_cvt_pk_f32_fp8((int)u1.y, false);
                A3 += __builtin_amdgcn_cvt_pk_f32_fp8((int)u1.y, true);
            }
            if (v2) {
                A0 += __builtin_amdgcn_cvt_pk_f32_fp8((int)u2.x, false);
                A1 += __builtin_amdgcn_cvt_pk_f32_fp8((int)u2.x, true);
                A2 += __builtin_amdgcn_cvt_pk_f32_fp8((int)u2.y, false);
                A3 += __builtin_amdgcn_cvt_pk_f32_fp8((int)u2.y, true);
            }
            if (v3) {
                A0 += __builtin_amdgcn_cvt_pk_f32_fp8((int)u3.x, false);
                A1 += __builtin_amdgcn_cvt_pk_f32_fp8((int)u3.x, true);
                A2 += __builtin_amdgcn_cvt_pk_f32_fp8((int)u3.y, false);
                A3 += __builtin_amdgcn_cvt_pk_f32_fp8((int)u3.y, true);
            }
        }
        for (; k < maxc; ++k) {                    // wave-uniform remainder
            int ei = e0 + k;
            int ridx = ei - P0;
            int s = __shfl(my_src, ridx & 63);
            if (ridx >= 64) s = srcs[ei];
            if (k < cnt) {
                uint2 u = x2p[(size_t)s * 16 + j];
                A0 += __builtin_amdgcn_cvt_pk_f32_fp8((int)u.x, false);
                A1 += __builtin_amdgcn_cvt_pk_f32_fp8((int)u.x, true);
                A2 += __builtin_amdgcn_cvt_pk_f32_fp8((int)u.y, false);
                A3 += __builtin_amdgcn_cvt_pk_f32_fp8((int)u.y, true);
            }
        }
        float inv = (cnt > 0) ? 1.0f / (float)cnt : 0.f;
        float2v iv = {inv, inv};
        A0 *= iv; A1 *= iv; A2 *= iv; A3 *= iv;
        int u0 = __builtin_amdgcn_cvt_pk_fp8_f32(A0.x, A0.y, 0, false);
        u0 = __builtin_amdgcn_cvt_pk_fp8_f32(A1.x, A1.y, u0, true);
        int u1 = __builtin_amdgcn_cvt_pk_fp8_f32(A2.x, A2.y, 0, false);
        u1 = __builtin_amdgcn_cvt_pk_fp8_f32(A3.x, A3.y, u1, true);
        if (nvalid) {
            uint2 v; v.x = (unsigned int)u0; v.y = (unsigned int)u1;
            // fragment order: plane r, group myn>>4, unit j, row myn&15
            Agf[(size_t)r * srows * 16 + (size_t)(myn >> 4) * 256 + j * 16 + (myn & 15)] = v;
        }
    }
}

// ---------------- dense MFMA GEMM: A from global fragments (no A LDS), B ping-pong ----
// EXACT round-15 kernel (r18's dual-epilogue variant regressed codegen 35->116 us).
#define BM2 128
__global__ __launch_bounds__(256) void k_gemm(
    const unsigned int* __restrict__ Ag8,   // [8] fragment-order planes
    const unsigned int* __restrict__ x8in,  // [N][32] fp8 rows (chunk 8 A)
    unsigned int* __restrict__ x8out,       // [N][32] fp8 rows
    const unsigned short* __restrict__ W8,  // [9][128n][64kp] fp8 pairs (this layer)
    const float* __restrict__ bias,         // [128]
    int d0, int srows)
{
    __shared__ __align__(16) ull Bls[4096];  // 2 x 16 KB ping-pong (B only)
    const int t = threadIdx.x;
    const int wv = t >> 6, lane = t & 63;
    const int quad = lane >> 4, l15 = lane & 15;
    const int m0 = d0 + blockIdx.x * BM2;

    float4v acc[2][8];
#pragma unroll
    for (int nt = 0; nt < 8; ++nt) {
        float bc = bias[nt * 16 + l15];
        acc[0][nt] = (float4v){bc, bc, bc, bc};
        acc[1][nt] = (float4v){bc, bc, bc, bc};
    }

    const size_t pstride = (size_t)srows * 16;      // ull per fragment plane
    const ull* Ag = (const ull*)Ag8 + ((size_t)((m0 - d0) >> 4) + 2 * wv) * 256;
    const ull* Xr = (const ull*)x8in;

    ull aC[8], aN[8], bR[8];
    {
        const ull* Wc = (const ull*)W8;
#pragma unroll
        for (int i = 0; i < 8; ++i) {
            aC[i] = Ag[(size_t)(i >> 2) * 256 + (i & 3) * 64 + lane];  // i = rt*4+kk
            bR[i] = Wc[t + 256 * i];
        }
    }
#pragma unroll
    for (int i = 0; i < 8; ++i) {
        int idx = t + 256 * i;
        Bls[gswz8(idx >> 4, idx & 15)] = bR[i];
    }
    __syncthreads();

    for (int c = 0; c < 9; ++c) {
        const int cur = (c & 1) * 2048;
        if (c < 8) {                               // prefetch next chunk under MFMA
            if (c + 1 < 8) {
                const ull* Ac = Ag + (size_t)(c + 1) * pstride;
#pragma unroll
                for (int i = 0; i < 8; ++i)
                    aN[i] = Ac[(size_t)(i >> 2) * 256 + (i & 3) * 64 + lane];
            } else {                               // root A from x8 rows (pi order)
#pragma unroll
                for (int i = 0; i < 8; ++i) {
                    int rt = i >> 2, kk = i & 3;
                    aN[i] = Xr[(size_t)(m0 + wv * 32 + rt * 16 + l15) * 16 + kk * 4 + quad];
                }
            }
            const ull* Wc = (const ull*)(W8 + (size_t)(c + 1) * 8192);
#pragma unroll
            for (int i = 0; i < 8; ++i) bR[i] = Wc[t + 256 * i];
        }
#pragma unroll
        for (int kk = 0; kk < 4; ++kk) {
            long long a0 = (long long)aC[kk];
            long long a1 = (long long)aC[4 + kk];
            int g = kk * 4 + quad;
#pragma unroll
            for (int nt = 0; nt < 8; ++nt) {
                long long b8 = (long long)Bls[cur + (nt * 16 + l15) * 16 + (g ^ l15)];
                acc[0][nt] = __builtin_amdgcn_mfma_f32_16x16x32_fp8_fp8(a0, b8, acc[0][nt], 0, 0, 0);
                acc[1][nt] = __builtin_amdgcn_mfma_f32_16x16x32_fp8_fp8(a1, b8, acc[1][nt], 0, 0, 0);
            }
        }
        if (c < 8) {
            const int nxt = ((c + 1) & 1) * 2048;
#pragma unroll
            for (int i = 0; i < 8; ++i) {
                int idx = t + 256 * i;
                Bls[nxt + gswz8(idx >> 4, idx & 15)] = bR[i];
                aC[i] = aN[i];
            }
            __syncthreads();
        }
    }
    // ---- epilogue: relu, fp8 pack (pi order rows) ----
    ull* outs = (ull*)x8out;
#pragma unroll
    for (int rt = 0; rt < 2; ++rt) {
#pragma unroll
        for (int i = 0; i < 4; ++i) {
            int row = m0 + wv * 32 + rt * 16 + quad * 4 + i;
            float v0 = acc[rt][0][i], v1 = acc[rt][1][i];
            float v2 = acc[rt][2][i], v3 = acc[rt][3][i];
            float v4 = acc[rt][4][i], v5 = acc[rt][5][i];
            float v6 = acc[rt][6][i], v7 = acc[rt][7][i];
            v0 = v0 > 0.f ? v0 : 0.f;  v1 = v1 > 0.f ? v1 : 0.f;
            v2 = v2 > 0.f ? v2 : 0.f;  v3 = v3 > 0.f ? v3 : 0.f;
            v4 = v4 > 0.f ? v4 : 0.f;  v5 = v5 > 0.f ? v5 : 0.f;
            v6 = v6 > 0.f ? v6 : 0.f;  v7 = v7 > 0.f ? v7 : 0.f;
            int lo = __builtin_amdgcn_cvt_pk_fp8_f32(v0, v1, 0, false);
            lo = __builtin_amdgcn_cvt_pk_fp8_f32(v2, v3, lo, true);
            int hi = __builtin_amdgcn_cvt_pk_fp8_f32(v4, v5, 0, false);
            hi = __builtin_amdgcn_cvt_pk_fp8_f32(v6, v7, hi, true);
            if (row < N_NODES) {
                ull w = ((ull)(unsigned int)hi << 32) | (unsigned int)lo;
                outs[(size_t)row * 16 + l15] = w;
            }
        }
    }
}

// ---------------- global mean pool (batch sorted): 64 nodes/wave, fp8 in ----------------
// gcnt comes from k_prep's binary search — no gcnt atomics here.
__global__ __launch_bounds__(256) void k_pool(const unsigned int* __restrict__ x8,
                                              const int* __restrict__ batch,
                                              float* __restrict__ gsum) {
    const int wv = threadIdx.x >> 6, lane = threadIdx.x & 63;
    const int n0 = (blockIdx.x * 4 + wv) * 64;
    if (n0 >= N_NODES) return;
    int n1 = n0 + 64;
    if (n1 > N_NODES) n1 = N_NODES;
    const int nb = n1 - n0;
    const unsigned short* xs = (const unsigned short*)x8;   // row = 64 ushorts
    int bb = batch[n0 + (lane < nb ? lane : nb - 1)];
    float2v A = {0.f, 0.f};
    int cur = __shfl(bb, 0);
    for (int base = 0; base < nb; base += 8) {
        unsigned int u[8];
        int m = nb - base;
#pragma unroll
        for (int qq = 0; qq < 8; ++qq)
            if (qq < m) u[qq] = xs[(size_t)(n0 + base + qq) * 64 + lane];
#pragma unroll
        for (int qq = 0; qq < 8; ++qq) {
            if (qq < m) {
                int b = __shfl(bb, base + qq);
                if (b != cur) {
                    atomicAdd(&gsum[cur * 128 + lane * 2], A.x);
                    atomicAdd(&gsum[cur * 128 + lane * 2 + 1], A.y);
                    A = (float2v){0.f, 0.f};
                    cur = b;
                }
                A += __builtin_amdgcn_cvt_pk_f32_fp8((int)u[qq], false);
            }
        }
    }
    atomicAdd(&gsum[cur * 128 + lane * 2], A.x);
    atomicAdd(&gsum[cur * 128 + lane * 2 + 1], A.y);
}

// ---------------- MLP heads (fp32; un-permutes g from pi byte-position order) ----------
__global__ __launch_bounds__(128) void k_heads(
    const float* __restrict__ gsum, const int* __restrict__ gcnt,
    const float* __restrict__ rw1, const float* __restrict__ rb1,
    const float* __restrict__ rw2, const float* __restrict__ rb2,
    const float* __restrict__ sw1, const float* __restrict__ sb1,
    const float* __restrict__ sw2, const float* __restrict__ sb2,
    float* __restrict__ out) {
    __shared__ float g[128];
    __shared__ float parts[2];
    int b = blockIdx.x, t = threadIdx.x;
    int c = gcnt[b];
    float invc = 1.0f / (float)(c > 0 ? c : 1);
    g[((t & 7) << 4) | (t >> 3)] = gsum[b * 128 + t] * invc;   // position -> natural col
    __syncthreads();
    float acc = rb1[t];
    for (int d = 0; d < 128; ++d) acc += g[d] * rw1[d * 128 + t];
    float h = acc > 0.f ? acc : 0.f;
    float p = h * rw2[t];
    for (int o = 32; o > 0; o >>= 1) p += __shfl_down(p, o);
    if ((t & 63) == 0) parts[t >> 6] = p;
    __syncthreads();
    if (t == 0) out[b] = parts[0] + parts[1] + rb2[0];
    __syncthreads();
    acc = sb1[t];
    for (int d = 0; d < 128; ++d) acc += g[d] * sw1[d * 128 + t];
    h = acc > 0.f ? acc : 0.f;
    p = h * sw2[t];
    for (int o = 32; o > 0; o >>= 1) p += __shfl_down(p, o);
    if ((t & 63) == 0) parts[t >> 6] = p;
    __syncthreads();
    if (t == 0) out[64 + b] = parts[0] + parts[1] + sb2[0];
}

extern "C" void kernel_launch(void* const* d_in, const int* in_sizes, int n_in,
                              void* d_out, int out_size, void* d_ws, size_t ws_size,
                              hipStream_t stream) {
    const int*   node_type  = (const int*)d_in[0];
    const int*   edge_index = (const int*)d_in[1];
    const int*   edge_type  = (const int*)d_in[2];
    const int*   batch      = (const int*)d_in[3];
    const float* node_emb   = (const float*)d_in[4];
    const float* rel_w      = (const float*)d_in[5];
    const float* root_w     = (const float*)d_in[6];
    const float* bias       = (const float*)d_in[7];
    const float* rw1        = (const float*)d_in[8];
    const float* rb1        = (const float*)d_in[9];
    const float* rw2        = (const float*)d_in[10];
    const float* rb2        = (const float*)d_in[11];
    const float* sw1        = (const float*)d_in[12];
    const float* sb1        = (const float*)d_in[13];
    const float* sw2        = (const float*)d_in[14];
    const float* sb2        = (const float*)d_in[15];
    float* out = (float*)d_out;

    char* ws = (char*)d_ws;
    size_t off = 0;
    auto alloc = [&](size_t bytes) -> void* {
        void* p = ws + off;
        off += (bytes + 255) & ~(size_t)255;
        return p;
    };
    // ---- persistent region ----
    unsigned int*   x8a    = (unsigned int*)alloc((size_t)N_NODES * 32 * 4);  // 12.8 MB
    unsigned int*   x8b    = (unsigned int*)alloc((size_t)N_NODES * 32 * 4);
    int*            rowptr = (int*)alloc((size_t)(NR + 1) * 4);
    int*            srcs   = (int*)alloc((size_t)N_EDGES * 4);
    int*            bsum   = (int*)alloc(1024 * 4);
    unsigned short* W8     = (unsigned short*)alloc((size_t)W8_TOTAL * 2);
    float*          gsum   = (float*)alloc((64 * 128 + 64) * 4);
    int*            gcnt   = (int*)(gsum + 64 * 128);
    size_t off_common = off;
    // ---- scratch region: sort temps, later overlapped by Ag8 slices ----
    int*            cursor = (int*)alloc((size_t)NR * 4);
    int*            counts = (int*)alloc((size_t)NR * 4);
    size_t off_sort = off;
    if (off_sort > ws_size) return;                // cannot run at all
    unsigned int*   Ag8    = (unsigned int*)(ws + off_common);  // overlaps cursor/counts
    size_t avail = ws_size - off_common;
    long max_rows = (avail > 32768) ? (long)((avail - 32768) / 1024) : 0;  // 32 KB tail slack
    int srows = (int)((max_rows / 128) * 128);     // multiple of BM2: no cross-slice reads
    if (srows > N_NODES + 127) srows = ((N_NODES + 127) / 128) * 128;
    if (srows < 128) return;                       // insufficient workspace — fail visibly

    // zero scratch via memset nodes (graph-capturable), then fused prep + edge sort
    hipMemsetAsync(counts, 0, (size_t)NR * 4, stream);
    hipMemsetAsync(gsum, 0, (size_t)(64 * 128 + 64) * 4, stream);
    k_prep<<<PB_TOTAL, 256, 0, stream>>>(edge_index, edge_type, counts,
                                         node_type, node_emb, x8a,
                                         rel_w, root_w, W8, batch, gcnt);
    k_scan1<<<NB1, 256, 0, stream>>>(counts, cursor, bsum);
    k_scan2<<<1, 1024, 0, stream>>>(bsum, NB1);
    k_scan3<<<(NR + 255) / 256, 256, 0, stream>>>(cursor, bsum, rowptr, cursor);
    k_scatter<<<(N_EDGES + 255) / 256, 256, 0, stream>>>(edge_index, edge_type, cursor, srcs);

    unsigned int* xcur = x8a;
    unsigned int* xnext = x8b;
    for (int l = 0; l < N_LAYER; ++l) {
        const unsigned short* W8l = W8 + (size_t)l * 9 * 8192;
        const float* bl = bias + (size_t)l * 128;
        for (int d0 = 0; d0 < N_NODES; d0 += srows) {
            int rows = N_NODES - d0;
            if (rows > srows) rows = srows;
            int ab = (rows + 15) / 16;                 // 16 nodes per block (4 waves x 4)
            int gb = (rows + BM2 - 1) / BM2;
            k_agg<<<ab, 256, 0, stream>>>(xcur, rowptr, srcs, Ag8, d0, rows, srows);
            k_gemm<<<gb, 256, 0, stream>>>(Ag8, xcur, xnext, W8l, bl, d0, srows);
        }
        unsigned int* tmp = xcur; xcur = xnext; xnext = tmp;
    }

    // pool + heads (final activations are in xcur after swap)
    k_pool<<<(N_NODES + 255) / 256, 256, 0, stream>>>(xcur, batch, gsum);
    k_heads<<<64, 128, 0, stream>>>(gsum, gcnt, rw1, rb1, rw2, rb2,
                                    sw1, sb1, sw2, sb2, out);
}

// Round 21
// 415.300 us; speedup vs baseline: 1.0162x; 1.0162x over previous
//
#include <hip/hip_runtime.h>
#include <hip/hip_bf16.h>

#define N_NODES 100000
#define N_EDGES 600000
#define DIM     128
#define N_REL   8
#define N_GRAPH 64
#define N_LAYER 3
#define NR      (N_NODES * N_REL)   // 800000
#define NB1     782                 // ceil(NR / 1024)

typedef __attribute__((ext_vector_type(4))) float float4v;
typedef __attribute__((ext_vector_type(2))) float float2v;
typedef unsigned long long ull;

// XOR-swizzle, 8-B granules, 128-B rows (B fp8 tiles): 16 granules/row
__device__ __forceinline__ int gswz8(int row, int g) {
    return row * 16 + (g ^ (row & 15));
}

// ---------------- fused prep: edge hist + x0 gather + weight prep + gcnt ----------------
#define W8_TOTAL (N_LAYER * 9 * 8192)   // 221184
#define PB_HIST  2344                   // ceil(600000/256)
#define PB_GATH  12500                  // 100000*32/256
#define PB_WPRE  864                    // 221184/256
#define PB_BCNT  1                      // binary-search block (NO atomics — r17's 100k
                                        // contended atomicAdds onto 64 ints cost 540 us)
#define PB_TOTAL (PB_HIST + PB_GATH + PB_WPRE + PB_BCNT)

__global__ __launch_bounds__(256) void k_prep(
    const int* __restrict__ ei, const int* __restrict__ et, int* __restrict__ counts,
    const int* __restrict__ nt, const float* __restrict__ emb, unsigned int* __restrict__ x8,
    const float* __restrict__ relw, const float* __restrict__ rootw,
    unsigned short* __restrict__ W8,
    const int* __restrict__ batch, int* __restrict__ gcnt)
{
    const int b = blockIdx.x, t = threadIdx.x;
    if (b < PB_HIST) {
        int e = b * 256 + t;
        if (e < N_EDGES) {
            int seg = ei[N_EDGES + e] * N_REL + et[e];
            atomicAdd(&counts[seg], 1);
        }
    } else if (b < PB_HIST + PB_GATH) {
        int gid = (b - PB_HIST) * 256 + t;        // < N_NODES*32 exactly
        int n = gid >> 5, up = gid & 31;
        const float* row = emb + (size_t)nt[n] * DIM;
        int p0 = up * 4;
        float f0 = row[((p0 + 0) & 7) * 16 + ((p0 + 0) >> 3)];
        float f1 = row[((p0 + 1) & 7) * 16 + ((p0 + 1) >> 3)];
        float f2 = row[((p0 + 2) & 7) * 16 + ((p0 + 2) >> 3)];
        float f3 = row[((p0 + 3) & 7) * 16 + ((p0 + 3) >> 3)];
        int u = __builtin_amdgcn_cvt_pk_fp8_f32(f0, f1, 0, false);
        u = __builtin_amdgcn_cvt_pk_fp8_f32(f2, f3, u, true);
        x8[gid] = (unsigned int)u;
    } else if (b < PB_HIST + PB_GATH + PB_WPRE) {
        int gid = (b - PB_HIST - PB_GATH) * 256 + t;   // < W8_TOTAL exactly
        int l = gid / (9 * 8192);
        int rem = gid - l * 9 * 8192;
        int r = rem >> 13;                 // plane 0..8
        int idx = rem & 8191;
        int n = idx >> 6, p2 = idx & 63;
        int pos0 = 2 * p2, pos1 = 2 * p2 + 1;
        int k0 = (pos0 & 7) * 16 + (pos0 >> 3);
        int k1 = (pos1 & 7) * 16 + (pos1 >> 3);
        float w0, w1;
        if (r < 8) {
            const float* base = relw + ((size_t)(l * 8 + r) * 128) * 128 + n;
            w0 = base[(size_t)k0 * 128];
            w1 = base[(size_t)k1 * 128];
        } else {
            const float* base = rootw + (size_t)l * 128 * 128 + n;
            w0 = base[(size_t)k0 * 128];
            w1 = base[(size_t)k1 * 128];
        }
        int pk = __builtin_amdgcn_cvt_pk_fp8_f32(w0, w1, 0, false);
        W8[gid] = (unsigned short)(pk & 0xffff);
    } else {
        // gcnt via binary search over sorted batch (plain stores, no atomics)
        int g = t;
        if (g < N_GRAPH) {
            int lo = 0, hi = N_NODES;
            while (lo < hi) { int mid = (lo + hi) >> 1; if (batch[mid] < g) lo = mid + 1; else hi = mid; }
            int start = lo;
            lo = 0; hi = N_NODES;
            while (lo < hi) { int mid = (lo + hi) >> 1; if (batch[mid] < g + 1) lo = mid + 1; else hi = mid; }
            gcnt[g] = lo - start;
        }
    }
}

__global__ __launch_bounds__(256) void k_scan1(const int* __restrict__ cnts,
                                               int* __restrict__ part,
                                               int* __restrict__ bsum) {
    __shared__ int sh[256];
    int t = threadIdx.x;
    int base = blockIdx.x * 1024 + t * 4;
    int v0 = (base + 0 < NR) ? cnts[base + 0] : 0;
    int v1 = (base + 1 < NR) ? cnts[base + 1] : 0;
    int v2 = (base + 2 < NR) ? cnts[base + 2] : 0;
    int v3 = (base + 3 < NR) ? cnts[base + 3] : 0;
    int tot = v0 + v1 + v2 + v3;
    sh[t] = tot;
    __syncthreads();
    for (int off = 1; off < 256; off <<= 1) {
        int x = (t >= off) ? sh[t - off] : 0;
        __syncthreads();
        sh[t] += x;
        __syncthreads();
    }
    int exc = sh[t] - tot;
    if (base + 0 < NR) part[base + 0] = exc;
    if (base + 1 < NR) part[base + 1] = exc + v0;
    if (base + 2 < NR) part[base + 2] = exc + v0 + v1;
    if (base + 3 < NR) part[base + 3] = exc + v0 + v1 + v2;
    if (t == 255) bsum[blockIdx.x] = sh[t];
}

__global__ __launch_bounds__(1024) void k_scan2(int* __restrict__ bsum, int nb) {
    __shared__ int sh[1024];
    int t = threadIdx.x;
    int v = (t < nb) ? bsum[t] : 0;
    sh[t] = v;
    __syncthreads();
    for (int off = 1; off < 1024; off <<= 1) {
        int x = (t >= off) ? sh[t - off] : 0;
        __syncthreads();
        sh[t] += x;
        __syncthreads();
    }
    if (t < nb) bsum[t] = sh[t] - v;   // exclusive block offsets
}

__global__ void k_scan3(const int* __restrict__ part, const int* __restrict__ bsum,
                        int* __restrict__ rowptr, int* __restrict__ cursor) {
    int i = blockIdx.x * 256 + threadIdx.x;
    if (i < NR) {
        int v = part[i] + bsum[i >> 10];
        rowptr[i] = v;
        cursor[i] = v;
    }
    if (i == 0) rowptr[NR] = N_EDGES;
}

__global__ void k_scatter(const int* __restrict__ ei, const int* __restrict__ et,
                          int* __restrict__ cursor, int* __restrict__ srcs) {
    int e = blockIdx.x * 256 + threadIdx.x;
    if (e < N_EDGES) {
        int seg = ei[N_EDGES + e] * N_REL + et[e];
        int p = atomicAdd(&cursor[seg], 1);
        srcs[p] = ei[e];
    }
}

// ---------------- per-dst aggregation: 4 nodes/wave, fp8 in, FRAGMENT-ORDER fp8 out ----
// Quarter q (16 lanes) owns node 4w+q; lane j covers byte positions 8j..8j+7.
// Wave-uniform maxc loop: every __shfl executes with all 64 lanes active (bpermute
// returns 0 from EXEC-inactive source lanes — divergent-loop shfl is UB; see r14).
// Unroll-2 is optimal: r20's unroll-4 regressed (avg maxc ~1.9, masked work dominates).
__global__ __launch_bounds__(256) void k_agg(
    const unsigned int* __restrict__ x8,    // [N][32] fp8 rows (pi order)
    const int* __restrict__ rowptr,         // [NR+1], seg = dst*8 + rel
    const int* __restrict__ srcs,           // [E] sorted by seg
    unsigned int* __restrict__ Ag8,         // [8] fragment-order planes
    int d0, int rows, int srows)
{
    const int t = threadIdx.x;
    const int wv = t >> 6, lane = t & 63;
    const int q = lane >> 4, j = lane & 15;
    const int nb0 = (blockIdx.x * 4 + wv) * 4;     // first local node of this wave
    if (nb0 >= rows) return;
    const int myn = nb0 + q;
    const bool nvalid = (myn < rows);

    int pr = 0;
    {
        int idx = (d0 + nb0) * 8 + lane;
        if (idx > NR) idx = NR;
        if (lane < 33) pr = rowptr[idx];
    }
    const int P0 = __shfl(pr, 0);
    const int Dtot = __shfl(pr, 32) - P0;

    int my_src = 0;
    if (lane < Dtot) my_src = srcs[P0 + lane];

    const uint2* x2p = (const uint2*)x8;           // row = 16 uint2
    uint2* Agf = (uint2*)Ag8;

    for (int r = 0; r < 8; ++r) {
        int e0 = __shfl(pr, q * 8 + r);
        int e1 = __shfl(pr, q * 8 + r + 1);
        int cnt = e1 - e0;                         // quarter-uniform
        int m1 = max(cnt, __shfl_xor(cnt, 16));
        int maxc = max(m1, __shfl_xor(m1, 32));    // wave max
        float2v A0 = {0.f, 0.f}, A1 = {0.f, 0.f}, A2 = {0.f, 0.f}, A3 = {0.f, 0.f};
        int k = 0;
        for (; k + 2 <= maxc; k += 2) {            // wave-uniform loop
            int ei0 = e0 + k, ei1 = e0 + k + 1;
            int r0 = ei0 - P0, r1 = ei1 - P0;
            int s0 = __shfl(my_src, r0 & 63);
            int s1 = __shfl(my_src, r1 & 63);
            if (r0 >= 64) s0 = srcs[ei0];          // essentially never
            if (r1 >= 64) s1 = srcs[ei1];
            bool v0 = (k < cnt), v1 = (k + 1 < cnt);
            uint2 u0, u1;
            if (v0) u0 = x2p[(size_t)s0 * 16 + j];
            if (v1) u1 = x2p[(size_t)s1 * 16 + j];
            if (v0) {
                A0 += __builtin_amdgcn_cvt_pk_f32_fp8((int)u0.x, false);
                A1 += __builtin_amdgcn_cvt_pk_f32_fp8((int)u0.x, true);
                A2 += __builtin_amdgcn_cvt_pk_f32_fp8((int)u0.y, false);
                A3 += __builtin_amdgcn_cvt_pk_f32_fp8((int)u0.y, true);
            }
            if (v1) {
                A0 += __builtin_amdgcn_cvt_pk_f32_fp8((int)u1.x, false);
                A1 += __builtin_amdgcn_cvt_pk_f32_fp8((int)u1.x, true);
                A2 += __builtin_amdgcn_cvt_pk_f32_fp8((int)u1.y, false);
                A3 += __builtin_amdgcn_cvt_pk_f32_fp8((int)u1.y, true);
            }
        }
        if (k < maxc) {
            int ei = e0 + k;
            int ridx = ei - P0;
            int s = __shfl(my_src, ridx & 63);
            if (ridx >= 64) s = srcs[ei];
            if (k < cnt) {
                uint2 u = x2p[(size_t)s * 16 + j];
                A0 += __builtin_amdgcn_cvt_pk_f32_fp8((int)u.x, false);
                A1 += __builtin_amdgcn_cvt_pk_f32_fp8((int)u.x, true);
                A2 += __builtin_amdgcn_cvt_pk_f32_fp8((int)u.y, false);
                A3 += __builtin_amdgcn_cvt_pk_f32_fp8((int)u.y, true);
            }
        }
        float inv = (cnt > 0) ? 1.0f / (float)cnt : 0.f;
        float2v iv = {inv, inv};
        A0 *= iv; A1 *= iv; A2 *= iv; A3 *= iv;
        int u0 = __builtin_amdgcn_cvt_pk_fp8_f32(A0.x, A0.y, 0, false);
        u0 = __builtin_amdgcn_cvt_pk_fp8_f32(A1.x, A1.y, u0, true);
        int u1 = __builtin_amdgcn_cvt_pk_fp8_f32(A2.x, A2.y, 0, false);
        u1 = __builtin_amdgcn_cvt_pk_fp8_f32(A3.x, A3.y, u1, true);
        if (nvalid) {
            uint2 v; v.x = (unsigned int)u0; v.y = (unsigned int)u1;
            // fragment order: plane r, group myn>>4, unit j, row myn&15
            Agf[(size_t)r * srows * 16 + (size_t)(myn >> 4) * 256 + j * 16 + (myn & 15)] = v;
        }
    }
}

// ---------------- dense MFMA GEMM: A from global fragments (no A LDS), B ping-pong ----
// EXACT round-15 kernel (r18's dual-epilogue variant regressed codegen 35->116 us).
#define BM2 128
__global__ __launch_bounds__(256) void k_gemm(
    const unsigned int* __restrict__ Ag8,   // [8] fragment-order planes
    const unsigned int* __restrict__ x8in,  // [N][32] fp8 rows (chunk 8 A)
    unsigned int* __restrict__ x8out,       // [N][32] fp8 rows
    const unsigned short* __restrict__ W8,  // [9][128n][64kp] fp8 pairs (this layer)
    const float* __restrict__ bias,         // [128]
    int d0, int srows)
{
    __shared__ __align__(16) ull Bls[4096];  // 2 x 16 KB ping-pong (B only)
    const int t = threadIdx.x;
    const int wv = t >> 6, lane = t & 63;
    const int quad = lane >> 4, l15 = lane & 15;
    const int m0 = d0 + blockIdx.x * BM2;

    float4v acc[2][8];
#pragma unroll
    for (int nt = 0; nt < 8; ++nt) {
        float bc = bias[nt * 16 + l15];
        acc[0][nt] = (float4v){bc, bc, bc, bc};
        acc[1][nt] = (float4v){bc, bc, bc, bc};
    }

    const size_t pstride = (size_t)srows * 16;      // ull per fragment plane
    const ull* Ag = (const ull*)Ag8 + ((size_t)((m0 - d0) >> 4) + 2 * wv) * 256;
    const ull* Xr = (const ull*)x8in;

    ull aC[8], aN[8], bR[8];
    {
        const ull* Wc = (const ull*)W8;
#pragma unroll
        for (int i = 0; i < 8; ++i) {
            aC[i] = Ag[(size_t)(i >> 2) * 256 + (i & 3) * 64 + lane];  // i = rt*4+kk
            bR[i] = Wc[t + 256 * i];
        }
    }
#pragma unroll
    for (int i = 0; i < 8; ++i) {
        int idx = t + 256 * i;
        Bls[gswz8(idx >> 4, idx & 15)] = bR[i];
    }
    __syncthreads();

    for (int c = 0; c < 9; ++c) {
        const int cur = (c & 1) * 2048;
        if (c < 8) {                               // prefetch next chunk under MFMA
            if (c + 1 < 8) {
                const ull* Ac = Ag + (size_t)(c + 1) * pstride;
#pragma unroll
                for (int i = 0; i < 8; ++i)
                    aN[i] = Ac[(size_t)(i >> 2) * 256 + (i & 3) * 64 + lane];
            } else {                               // root A from x8 rows (pi order)
#pragma unroll
                for (int i = 0; i < 8; ++i) {
                    int rt = i >> 2, kk = i & 3;
                    aN[i] = Xr[(size_t)(m0 + wv * 32 + rt * 16 + l15) * 16 + kk * 4 + quad];
                }
            }
            const ull* Wc = (const ull*)(W8 + (size_t)(c + 1) * 8192);
#pragma unroll
            for (int i = 0; i < 8; ++i) bR[i] = Wc[t + 256 * i];
        }
#pragma unroll
        for (int kk = 0; kk < 4; ++kk) {
            long long a0 = (long long)aC[kk];
            long long a1 = (long long)aC[4 + kk];
            int g = kk * 4 + quad;
#pragma unroll
            for (int nt = 0; nt < 8; ++nt) {
                long long b8 = (long long)Bls[cur + (nt * 16 + l15) * 16 + (g ^ l15)];
                acc[0][nt] = __builtin_amdgcn_mfma_f32_16x16x32_fp8_fp8(a0, b8, acc[0][nt], 0, 0, 0);
                acc[1][nt] = __builtin_amdgcn_mfma_f32_16x16x32_fp8_fp8(a1, b8, acc[1][nt], 0, 0, 0);
            }
        }
        if (c < 8) {
            const int nxt = ((c + 1) & 1) * 2048;
#pragma unroll
            for (int i = 0; i < 8; ++i) {
                int idx = t + 256 * i;
                Bls[nxt + gswz8(idx >> 4, idx & 15)] = bR[i];
                aC[i] = aN[i];
            }
            __syncthreads();
        }
    }
    // ---- epilogue: relu, fp8 pack (pi order rows) ----
    ull* outs = (ull*)x8out;
#pragma unroll
    for (int rt = 0; rt < 2; ++rt) {
#pragma unroll
        for (int i = 0; i < 4; ++i) {
            int row = m0 + wv * 32 + rt * 16 + quad * 4 + i;
            float v0 = acc[rt][0][i], v1 = acc[rt][1][i];
            float v2 = acc[rt][2][i], v3 = acc[rt][3][i];
            float v4 = acc[rt][4][i], v5 = acc[rt][5][i];
            float v6 = acc[rt][6][i], v7 = acc[rt][7][i];
            v0 = v0 > 0.f ? v0 : 0.f;  v1 = v1 > 0.f ? v1 : 0.f;
            v2 = v2 > 0.f ? v2 : 0.f;  v3 = v3 > 0.f ? v3 : 0.f;
            v4 = v4 > 0.f ? v4 : 0.f;  v5 = v5 > 0.f ? v5 : 0.f;
            v6 = v6 > 0.f ? v6 : 0.f;  v7 = v7 > 0.f ? v7 : 0.f;
            int lo = __builtin_amdgcn_cvt_pk_fp8_f32(v0, v1, 0, false);
            lo = __builtin_amdgcn_cvt_pk_fp8_f32(v2, v3, lo, true);
            int hi = __builtin_amdgcn_cvt_pk_fp8_f32(v4, v5, 0, false);
            hi = __builtin_amdgcn_cvt_pk_fp8_f32(v6, v7, hi, true);
            if (row < N_NODES) {
                ull w = ((ull)(unsigned int)hi << 32) | (unsigned int)lo;
                outs[(size_t)row * 16 + l15] = w;
            }
        }
    }
}

// ---------------- global mean pool (batch sorted): 64 nodes/wave, fp8 in ----------------
// gcnt comes from k_prep's binary search — no gcnt atomics here.
__global__ __launch_bounds__(256) void k_pool(const unsigned int* __restrict__ x8,
                                              const int* __restrict__ batch,
                                              float* __restrict__ gsum) {
    const int wv = threadIdx.x >> 6, lane = threadIdx.x & 63;
    const int n0 = (blockIdx.x * 4 + wv) * 64;
    if (n0 >= N_NODES) return;
    int n1 = n0 + 64;
    if (n1 > N_NODES) n1 = N_NODES;
    const int nb = n1 - n0;
    const unsigned short* xs = (const unsigned short*)x8;   // row = 64 ushorts
    int bb = batch[n0 + (lane < nb ? lane : nb - 1)];
    float2v A = {0.f, 0.f};
    int cur = __shfl(bb, 0);
    for (int base = 0; base < nb; base += 8) {
        unsigned int u[8];
        int m = nb - base;
#pragma unroll
        for (int qq = 0; qq < 8; ++qq)
            if (qq < m) u[qq] = xs[(size_t)(n0 + base + qq) * 64 + lane];
#pragma unroll
        for (int qq = 0; qq < 8; ++qq) {
            if (qq < m) {
                int b = __shfl(bb, base + qq);
                if (b != cur) {
                    atomicAdd(&gsum[cur * 128 + lane * 2], A.x);
                    atomicAdd(&gsum[cur * 128 + lane * 2 + 1], A.y);
                    A = (float2v){0.f, 0.f};
                    cur = b;
                }
                A += __builtin_amdgcn_cvt_pk_f32_fp8((int)u[qq], false);
            }
        }
    }
    atomicAdd(&gsum[cur * 128 + lane * 2], A.x);
    atomicAdd(&gsum[cur * 128 + lane * 2 + 1], A.y);
}

// ---------------- MLP heads (fp32; un-permutes g from pi byte-position order) ----------
__global__ __launch_bounds__(128) void k_heads(
    const float* __restrict__ gsum, const int* __restrict__ gcnt,
    const float* __restrict__ rw1, const float* __restrict__ rb1,
    const float* __restrict__ rw2, const float* __restrict__ rb2,
    const float* __restrict__ sw1, const float* __restrict__ sb1,
    const float* __restrict__ sw2, const float* __restrict__ sb2,
    float* __restrict__ out) {
    __shared__ float g[128];
    __shared__ float parts[2];
    int b = blockIdx.x, t = threadIdx.x;
    int c = gcnt[b];
    float invc = 1.0f / (float)(c > 0 ? c : 1);
    g[((t & 7) << 4) | (t >> 3)] = gsum[b * 128 + t] * invc;   // position -> natural col
    __syncthreads();
    float acc = rb1[t];
    for (int d = 0; d < 128; ++d) acc += g[d] * rw1[d * 128 + t];
    float h = acc > 0.f ? acc : 0.f;
    float p = h * rw2[t];
    for (int o = 32; o > 0; o >>= 1) p += __shfl_down(p, o);
    if ((t & 63) == 0) parts[t >> 6] = p;
    __syncthreads();
    if (t == 0) out[b] = parts[0] + parts[1] + rb2[0];
    __syncthreads();
    acc = sb1[t];
    for (int d = 0; d < 128; ++d) acc += g[d] * sw1[d * 128 + t];
    h = acc > 0.f ? acc : 0.f;
    p = h * sw2[t];
    for (int o = 32; o > 0; o >>= 1) p += __shfl_down(p, o);
    if ((t & 63) == 0) parts[t >> 6] = p;
    __syncthreads();
    if (t == 0) out[64 + b] = parts[0] + parts[1] + sb2[0];
}

extern "C" void kernel_launch(void* const* d_in, const int* in_sizes, int n_in,
                              void* d_out, int out_size, void* d_ws, size_t ws_size,
                              hipStream_t stream) {
    const int*   node_type  = (const int*)d_in[0];
    const int*   edge_index = (const int*)d_in[1];
    const int*   edge_type  = (const int*)d_in[2];
    const int*   batch      = (const int*)d_in[3];
    const float* node_emb   = (const float*)d_in[4];
    const float* rel_w      = (const float*)d_in[5];
    const float* root_w     = (const float*)d_in[6];
    const float* bias       = (const float*)d_in[7];
    const float* rw1        = (const float*)d_in[8];
    const float* rb1        = (const float*)d_in[9];
    const float* rw2        = (const float*)d_in[10];
    const float* rb2        = (const float*)d_in[11];
    const float* sw1        = (const float*)d_in[12];
    const float* sb1        = (const float*)d_in[13];
    const float* sw2        = (const float*)d_in[14];
    const float* sb2        = (const float*)d_in[15];
    float* out = (float*)d_out;

    char* ws = (char*)d_ws;
    size_t off = 0;
    auto alloc = [&](size_t bytes) -> void* {
        void* p = ws + off;
        off += (bytes + 255) & ~(size_t)255;
        return p;
    };
    // ---- persistent region ----
    unsigned int*   x8a    = (unsigned int*)alloc((size_t)N_NODES * 32 * 4);  // 12.8 MB
    unsigned int*   x8b    = (unsigned int*)alloc((size_t)N_NODES * 32 * 4);
    int*            rowptr = (int*)alloc((size_t)(NR + 1) * 4);
    int*            srcs   = (int*)alloc((size_t)N_EDGES * 4);
    int*            bsum   = (int*)alloc(1024 * 4);
    unsigned short* W8     = (unsigned short*)alloc((size_t)W8_TOTAL * 2);
    float*          gsum   = (float*)alloc((64 * 128 + 64) * 4);
    int*            gcnt   = (int*)(gsum + 64 * 128);
    size_t off_common = off;
    // ---- scratch region: sort temps, later overlapped by Ag8 slices ----
    int*            cursor = (int*)alloc((size_t)NR * 4);
    int*            counts = (int*)alloc((size_t)NR * 4);
    size_t off_sort = off;
    if (off_sort > ws_size) return;                // cannot run at all
    unsigned int*   Ag8    = (unsigned int*)(ws + off_common);  // overlaps cursor/counts
    size_t avail = ws_size - off_common;
    long max_rows = (avail > 32768) ? (long)((avail - 32768) / 1024) : 0;  // 32 KB tail slack
    int srows = (int)((max_rows / 128) * 128);     // multiple of BM2: no cross-slice reads
    if (srows > N_NODES + 127) srows = ((N_NODES + 127) / 128) * 128;
    if (srows < 128) return;                       // insufficient workspace — fail visibly

    // zero scratch via memset nodes (graph-capturable), then fused prep + edge sort
    hipMemsetAsync(counts, 0, (size_t)NR * 4, stream);
    hipMemsetAsync(gsum, 0, (size_t)(64 * 128 + 64) * 4, stream);
    k_prep<<<PB_TOTAL, 256, 0, stream>>>(edge_index, edge_type, counts,
                                         node_type, node_emb, x8a,
                                         rel_w, root_w, W8, batch, gcnt);
    k_scan1<<<NB1, 256, 0, stream>>>(counts, cursor, bsum);
    k_scan2<<<1, 1024, 0, stream>>>(bsum, NB1);
    k_scan3<<<(NR + 255) / 256, 256, 0, stream>>>(cursor, bsum, rowptr, cursor);
    k_scatter<<<(N_EDGES + 255) / 256, 256, 0, stream>>>(edge_index, edge_type, cursor, srcs);

    unsigned int* xcur = x8a;
    unsigned int* xnext = x8b;
    for (int l = 0; l < N_LAYER; ++l) {
        const unsigned short* W8l = W8 + (size_t)l * 9 * 8192;
        const float* bl = bias + (size_t)l * 128;
        for (int d0 = 0; d0 < N_NODES; d0 += srows) {
            int rows = N_NODES - d0;
            if (rows > srows) rows = srows;
            int ab = (rows + 15) / 16;                 // 16 nodes per block (4 waves x 4)
            int gb = (rows + BM2 - 1) / BM2;
            k_agg<<<ab, 256, 0, stream>>>(xcur, rowptr, srcs, Ag8, d0, rows, srows);
            k_gemm<<<gb, 256, 0, stream>>>(Ag8, xcur, xnext, W8l, bl, d0, srows);
        }
        unsigned int* tmp = xcur; xcur = xnext; xnext = tmp;
    }

    // pool + heads (final activations are in xcur after swap)
    k_pool<<<(N_NODES + 255) / 256, 256, 0, stream>>>(xcur, batch, gsum);
    k_heads<<<64, 128, 0, stream>>>(gsum, gcnt, rw1, rb1, rw2, rb2,
                                    sw1, sb1, sw2, sb2, out);
}